// Round 21
// baseline (282.684 us; speedup 1.0000x reference)
//
#include <hip/hip_runtime.h>
#include <math.h>

// ---------------------------------------------------------------------------
// R15 (2nd resubmit; prior benches were GPUAcquisitionTimeout, never ran):
//     R14 + pad-slot initialization fix.
//     R14 CRASHED (core dump): edge-parallel phase A gathers ALL slots in
//     [0, ptot) including 4-align row-padding slots, which the counting sort
//     never writes -> garbage LDS -> t[garbage] -> illegal address. Fix:
//     zero s_out[0..ptot) before the sort scatter (pad gathers become t[0],
//     excluded from sums by the slot-in-row guard).
//     Measured lessons:
//       R5: per-EDGE LDS/flat atomic feature accumulation = 183 us/layer.
//       R6: node-exact global scatter = 260 us. R8: few-block big-LDS starve.
//       R11: mega-fusion pinning LDS = 217 us alone. Never.
//       R12+R13: scatter time INVARIANT to write-bytes (24<->51 MB) and to
//           blocks >=196 (47-50 us floor). Parked at CHUNK=8192 (R13=226.7).
//     Structure: gcn2/agg3 edge-parallel two-phase: phase A = 12 independent
//     gathers per thread (no index->gather chain); phase B = boundary walk,
//     register runs, ~1-2 LDS-atomic flushes into acc[128][9].
// ---------------------------------------------------------------------------

#define CHUNK     8192    // edges per scatter block (391 blocks)
#define BW        128     // nodes per bucket (dst >> 7)
#define MAXNB     800     // >= NB = 782
#define MAXB_RAW  5376    // raw edges clamp per bucket (mean 4092, +20 sigma)
#define MAXB_PAD  5760    // padded rows clamp (raw + 128*3)
#define REGION    5760    // fixed region stride (ints); 16B-aligned
#define SLT       12      // slots per thread in edge-parallel phase (512*12>=5760)

typedef _Float16 half8 __attribute__((ext_vector_type(8)));

static __device__ __forceinline__ float sigmoidf_(float x) {
    return 1.0f / (1.0f + expf(-x));
}

// exclusive 256-scan; s[255] holds inclusive total afterwards
static __device__ __forceinline__ int scan256_excl(int v, int* s) {
    int tid = threadIdx.x;
    s[tid] = v;
    for (int off = 1; off < 256; off <<= 1) {
        __syncthreads();
        int t = (tid >= off) ? s[tid - off] : 0;
        __syncthreads();
        s[tid] += t;
    }
    __syncthreads();
    return s[tid] - v;
}

// ---- fused: transform1 (blocks [0,nbT)) + hist/reserve/scatter -----------
__global__ __launch_bounds__(512)
void setup_scatter_kernel(const float* __restrict__ x, const float* __restrict__ Wrel,
                          const float* __restrict__ bias, const float* __restrict__ Wroot,
                          _Float16* __restrict__ t1, _Float16* __restrict__ z1,
                          const int* __restrict__ src, const int* __restrict__ dst,
                          int* __restrict__ gcur, unsigned* __restrict__ stage,
                          int N, int E, int NB, int nbT) {
    __shared__ float sWr[128], sWo[128], sb[8];
    __shared__ int s_hist[MAXNB];
    __shared__ int s_cur[MAXNB];
    int tid = threadIdx.x, blk = blockIdx.x;

    if (blk < nbT) {
        // ---- transform: t1 = x@Wr1, z1 = x@Wo1 + b1 ----
        if (tid < 128) { sWr[tid] = Wrel[tid]; sWo[tid] = Wroot[tid]; }
        if (tid >= 128 && tid < 136) sb[tid - 128] = bias[tid - 128];
        __syncthreads();
        int node = blk * 512 + tid;
        if (node >= N) return;
        const float4* x4 = (const float4*)x;
        float xv[16];
#pragma unroll
        for (int k = 0; k < 4; ++k) {
            float4 v = x4[node * 4 + k];
            xv[4 * k] = v.x; xv[4 * k + 1] = v.y; xv[4 * k + 2] = v.z; xv[4 * k + 3] = v.w;
        }
        float ta[8], za[8];
#pragma unroll
        for (int j = 0; j < 8; ++j) { ta[j] = 0.0f; za[j] = sb[j]; }
#pragma unroll
        for (int f = 0; f < 16; ++f) {
            float xf = xv[f];
#pragma unroll
            for (int j = 0; j < 8; ++j) {
                ta[j] += xf * sWr[f * 8 + j];
                za[j] += xf * sWo[f * 8 + j];
            }
        }
        half8 th, zh;
#pragma unroll
        for (int j = 0; j < 8; ++j) { th[j] = (_Float16)ta[j]; zh[j] = (_Float16)za[j]; }
        ((half8*)t1)[node] = th;
        ((half8*)z1)[node] = zh;
    } else {
        // ---- per-chunk hist -> global reserve -> LDS-cursor scatter ----
        int chunk = blk - nbT;
        int base = chunk * CHUNK;
        int cnt = E - base; if (cnt > CHUNK) cnt = CHUNK;
        for (int i = tid; i < NB; i += 512) s_hist[i] = 0;
        __syncthreads();
        if (cnt == CHUNK) {
            const int4* d4 = (const int4*)(dst + base);
#pragma unroll
            for (int k = 0; k < CHUNK / 2048; ++k) {
                int4 d = d4[k * 512 + tid];
                atomicAdd(&s_hist[d.x >> 7], 1);
                atomicAdd(&s_hist[d.y >> 7], 1);
                atomicAdd(&s_hist[d.z >> 7], 1);
                atomicAdd(&s_hist[d.w >> 7], 1);
            }
        } else {
            for (int i = tid; i < cnt; i += 512) atomicAdd(&s_hist[dst[base + i] >> 7], 1);
        }
        __syncthreads();
        for (int i = tid; i < NB; i += 512) {
            int hh = s_hist[i];
            s_cur[i] = i * REGION + atomicAdd(&gcur[i], hh);
        }
        __syncthreads();
        if (cnt == CHUNK) {
            const int4* d4 = (const int4*)(dst + base);
            const int4* s4 = (const int4*)(src + base);
#pragma unroll
            for (int k = 0; k < CHUNK / 2048; ++k) {
                int4 d = d4[k * 512 + tid];
                int4 s = s4[k * 512 + tid];
                int dd[4] = {d.x, d.y, d.z, d.w};
                int ss[4] = {s.x, s.y, s.z, s.w};
#pragma unroll
                for (int j = 0; j < 4; ++j) {
                    int pos = atomicAdd(&s_cur[dd[j] >> 7], 1);
                    stage[pos] = ((unsigned)(dd[j] & 127) << 17) | (unsigned)ss[j];
                }
            }
        } else {
            for (int i = tid; i < cnt; i += 512) {
                int d = dst[base + i], s = src[base + i];
                int pos = atomicAdd(&s_cur[d >> 7], 1);
                stage[pos] = ((unsigned)(d & 127) << 17) | (unsigned)s;
            }
        }
    }
}

// ---- per-bucket counting sort (LDS-resident) + coalesced csr + agg1 ------
__global__ __launch_bounds__(256)
void csr_agg1_kernel(const unsigned* __restrict__ stage, const int* __restrict__ gcur,
                     int* __restrict__ csr, int* __restrict__ deg,
                     int* __restrict__ rowstart, int* __restrict__ ptot_arr,
                     const _Float16* __restrict__ t1, const _Float16* __restrict__ z1,
                     _Float16* __restrict__ h1, int N) {
    __shared__ unsigned __attribute__((aligned(16))) s_p[MAXB_RAW];
    __shared__ int __attribute__((aligned(16))) s_out[MAXB_PAD];
    __shared__ int h[BW], hs[BW], curb[BW];
    __shared__ int s_scan[256];
    int b = blockIdx.x, tid = threadIdx.x;
    int beg = b * REGION;
    int tot = gcur[b]; if (tot > MAXB_RAW) tot = MAXB_RAW;

    // coalesced region read into LDS
    const uint4* st4 = (const uint4*)(stage + beg);
    int n4 = tot >> 2;
    for (int i = tid; i < n4; i += 256) ((uint4*)s_p)[i] = st4[i];
    for (int i = (n4 << 2) + tid; i < tot; i += 256) s_p[i] = stage[beg + i];
    if (tid < BW) h[tid] = 0;
    __syncthreads();

    // per-node histogram
    for (int i = tid; i < tot; i += 256) atomicAdd(&h[s_p[i] >> 17], 1);
    __syncthreads();

    // exclusive scan of align4(deg) (tid >= BW contribute 0)
    int v = (tid < BW) ? ((h[tid] + 3) & ~3) : 0;
    int excl = scan256_excl(v, s_scan);
    int ptot = s_scan[255]; if (ptot > MAXB_PAD) ptot = MAXB_PAD;
    int dg = 0, myStart = 0;
    if (tid < BW) {
        dg = h[tid]; myStart = excl;
        hs[tid] = myStart; curb[tid] = myStart;
        int node = b * BW + tid;
        if (node < N) { deg[node] = dg; rowstart[node] = beg + myStart; }
    }
    if (tid == 0) ptot_arr[b] = ptot;
    // R15 FIX: zero padded range so 4-align pad slots hold index 0, not
    // garbage (R14 crashed: edge-parallel gathers read pad slots).
    for (int i = tid; i < ptot; i += 256) s_out[i] = 0;
    __syncthreads();

    // counting-sort scatter into LDS s_out
    for (int i = tid; i < tot; i += 256) {
        unsigned p = s_p[i];
        int pos = atomicAdd(&curb[p >> 17], 1);
        s_out[pos] = (int)(p & 0x1FFFF);
    }
    __syncthreads();

    // coalesced csr write (ptot is a multiple of 4)
    int p4 = ptot >> 2;
    int4* csr4 = (int4*)(csr + beg);
    for (int i = tid; i < p4; i += 256) csr4[i] = ((const int4*)s_out)[i];

    // layer-1 aggregation: 2 threads/node, indices from LDS, t1 from L2
    int nd = tid >> 1, half = tid & 1;
    int node = b * BW + nd;
    if (node < N) {
        int rs = hs[nd], d = h[nd];
        int d1 = ((d >> 1) + 3) & ~3; if (d1 > d) d1 = d;
        int from = half ? d1 : 0;
        int to   = half ? d  : d1;
        const half8* t = (const half8*)t1;
        float s[8];
#pragma unroll
        for (int c = 0; c < 8; ++c) s[c] = 0.0f;
        int e = from;
        for (; e + 4 <= to; e += 4) {
            int4 ci = *(const int4*)(s_out + rs + e);
            half8 v0 = t[ci.x]; half8 v1 = t[ci.y];
            half8 v2 = t[ci.z]; half8 v3 = t[ci.w];
#pragma unroll
            for (int c = 0; c < 8; ++c)
                s[c] += ((float)v0[c] + (float)v1[c]) + ((float)v2[c] + (float)v3[c]);
        }
        for (; e < to; ++e) {
            half8 vv = t[s_out[rs + e]];
#pragma unroll
            for (int c = 0; c < 8; ++c) s[c] += (float)vv[c];
        }
#pragma unroll
        for (int c = 0; c < 8; ++c) s[c] += __shfl_xor(s[c], 1);
        if (half == 0) {
            float inv = 1.0f / (float)(d > 0 ? d : 1);
            half8 z = ((const half8*)z1)[node];
            half8 o;
#pragma unroll
            for (int c = 0; c < 8; ++c) o[c] = (_Float16)sigmoidf_(s[c] * inv + (float)z[c]);
            ((half8*)h1)[node] = o;
        }
    }
}

// ---- shared edge-parallel accumulate: slots -> acc[128][9] ---------------
// Each thread: SLT consecutive slots; independent gathers; boundary walk;
// LDS atomic flush per row-run. rsl[129] ascending row starts (rsl[128]=ptot).
// Pad slots hold index 0 (valid); excluded from sums by the in-row guard.
static __device__ __forceinline__ void edge_accum(
    const half8* __restrict__ t, const int* __restrict__ csr, int beg, int ptot,
    const int* rsl, const int* dgl, float* acc) {
    int tid = threadIdx.x;
    int s0 = tid * SLT;
    if (s0 >= ptot) return;
    int sE = s0 + SLT; if (sE > ptot) sE = ptot;

    half8 g[SLT];
#pragma unroll
    for (int j = 0; j < SLT; ++j) {
        if (s0 + j < sE) g[j] = t[csr[beg + s0 + j]];   // independent gathers
    }

    // binary search: largest nd with rsl[nd] <= s0
    int lo = 0, hi = 127;
    while (lo < hi) { int mid = (lo + hi + 1) >> 1; if (rsl[mid] <= s0) lo = mid; else hi = mid - 1; }
    int nd = lo;

    float run[8];
#pragma unroll
    for (int c = 0; c < 8; ++c) run[c] = 0.0f;
    bool dirty = false;
#pragma unroll
    for (int j = 0; j < SLT; ++j) {
        int slot = s0 + j;
        if (slot >= sE) break;
        while (slot >= rsl[nd + 1]) {
            if (dirty) {
#pragma unroll
                for (int c = 0; c < 8; ++c) { atomicAdd(&acc[nd * 9 + c], run[c]); run[c] = 0.0f; }
                dirty = false;
            }
            ++nd;
        }
        if (slot - rsl[nd] < dgl[nd]) {
#pragma unroll
            for (int c = 0; c < 8; ++c) run[c] += (float)g[j][c];
            dirty = true;
        }
    }
    if (dirty) {
#pragma unroll
        for (int c = 0; c < 8; ++c) atomicAdd(&acc[nd * 9 + c], run[c]);
    }
}

// ---- layer 2 + layer-3 transform; edge-parallel, block = bucket ----------
__global__ __launch_bounds__(512)
void gcn2_edge_kernel(const _Float16* __restrict__ h1,
                      const int* __restrict__ rowstart, const int* __restrict__ deg,
                      const int* __restrict__ csr, const int* __restrict__ ptot_arr,
                      const float* __restrict__ W2r, const float* __restrict__ b2,
                      const float* __restrict__ W2o,
                      const float* __restrict__ W3r, const float* __restrict__ b3,
                      const float* __restrict__ W3o,
                      _Float16* __restrict__ t3, _Float16* __restrict__ z3, int N) {
    __shared__ float sW2r[128], sW2o[128], sW3r[128], sW3o[128], sb2[16], sb3[8];
    __shared__ float acc[BW * 9];
    __shared__ int rsl[BW + 1], dgl[BW];
    __shared__ int ptot_s;
    int b = blockIdx.x, tid = threadIdx.x;
    int beg = b * REGION;

    if (tid == 0) ptot_s = ptot_arr[b];
    if (tid < 128) { sW2r[tid] = W2r[tid]; sW2o[tid] = W2o[tid];
                     sW3r[tid] = W3r[tid]; sW3o[tid] = W3o[tid]; }
    if (tid < 16) sb2[tid] = b2[tid];
    if (tid < 8)  sb3[tid] = b3[tid];
    for (int i = tid; i < BW * 9; i += 512) acc[i] = 0.0f;
    __syncthreads();
    int ptot = ptot_s;
    if (tid < BW) {
        int node = b * BW + tid;
        rsl[tid] = (node < N) ? (rowstart[node] - beg) : ptot;
        dgl[tid] = (node < N) ? deg[node] : 0;
    }
    if (tid == 0) rsl[BW] = ptot;
    __syncthreads();

    edge_accum((const half8*)h1, csr, beg, ptot, rsl, dgl, acc);
    __syncthreads();

    if (tid < BW) {
        int node = b * BW + tid;
        if (node < N) {
            int d = dgl[tid];
            float inv = 1.0f / (float)(d > 0 ? d : 1);
            float m[8];
#pragma unroll
            for (int c = 0; c < 8; ++c) m[c] = acc[tid * 9 + c] * inv;
            half8 sf = ((const half8*)h1)[node];
            float x8[8];
#pragma unroll
            for (int c = 0; c < 8; ++c) x8[c] = (float)sf[c];
            float v16[16];
#pragma unroll
            for (int j = 0; j < 16; ++j) {
                float a = sb2[j];
#pragma unroll
                for (int f = 0; f < 8; ++f)
                    a += m[f] * sW2r[f * 16 + j] + x8[f] * sW2o[f * 16 + j];
                v16[j] = sigmoidf_(a);
            }
            float ta[8], za[8];
#pragma unroll
            for (int j = 0; j < 8; ++j) { ta[j] = 0.0f; za[j] = sb3[j]; }
#pragma unroll
            for (int f = 0; f < 16; ++f) {
                float hv = v16[f];
#pragma unroll
                for (int j = 0; j < 8; ++j) {
                    ta[j] += hv * sW3r[f * 8 + j];
                    za[j] += hv * sW3o[f * 8 + j];
                }
            }
            half8 th, zh;
#pragma unroll
            for (int j = 0; j < 8; ++j) { th[j] = (_Float16)ta[j]; zh[j] = (_Float16)za[j]; }
            ((half8*)t3)[node] = th;
            ((half8*)z3)[node] = zh;
        }
    }
}

// ---- layer 3 + MLP head; edge-parallel, block = bucket -------------------
__global__ __launch_bounds__(512)
void agg3_edge_kernel(const _Float16* __restrict__ t3, const _Float16* __restrict__ z3,
                      const int* __restrict__ rowstart, const int* __restrict__ deg,
                      const int* __restrict__ csr, const int* __restrict__ ptot_arr,
                      const float* __restrict__ fc1W, const float* __restrict__ fc1b,
                      const float* __restrict__ fc2W, const float* __restrict__ fc2b,
                      float* __restrict__ out, int N) {
    __shared__ float sW1[256], sb1[32], sW2[32];
    __shared__ float sb2_;
    __shared__ float acc[BW * 9];
    __shared__ int rsl[BW + 1], dgl[BW];
    __shared__ int ptot_s;
    int b = blockIdx.x, tid = threadIdx.x;
    int beg = b * REGION;

    if (tid == 0) { ptot_s = ptot_arr[b]; sb2_ = fc2b[0]; }
    if (tid < 256) sW1[tid] = fc1W[tid];
    if (tid < 32) { sb1[tid] = fc1b[tid]; sW2[tid] = fc2W[tid]; }
    for (int i = tid; i < BW * 9; i += 512) acc[i] = 0.0f;
    __syncthreads();
    int ptot = ptot_s;
    if (tid < BW) {
        int node = b * BW + tid;
        rsl[tid] = (node < N) ? (rowstart[node] - beg) : ptot;
        dgl[tid] = (node < N) ? deg[node] : 0;
    }
    if (tid == 0) rsl[BW] = ptot;
    __syncthreads();

    edge_accum((const half8*)t3, csr, beg, ptot, rsl, dgl, acc);
    __syncthreads();

    if (tid < BW) {
        int node = b * BW + tid;
        if (node < N) {
            int d = dgl[tid];
            float inv = 1.0f / (float)(d > 0 ? d : 1);
            half8 z = ((const half8*)z3)[node];
            float h[8];
#pragma unroll
            for (int c = 0; c < 8; ++c) h[c] = sigmoidf_(acc[tid * 9 + c] * inv + (float)z[c]);
            float a2 = sb2_;
#pragma unroll
            for (int j = 0; j < 32; ++j) {
                float a = sb1[j];
#pragma unroll
                for (int f = 0; f < 8; ++f) a += h[f] * sW1[f * 32 + j];
                a2 += sW2[j] * sigmoidf_(a);
            }
            out[node] = a2;
        }
    }
}

extern "C" void kernel_launch(void* const* d_in, const int* in_sizes, int n_in,
                              void* d_out, int out_size, void* d_ws, size_t ws_size,
                              hipStream_t stream) {
    const float* x      = (const float*)d_in[0];
    const int*   ei     = (const int*)d_in[1];
    const float* Wrel1  = (const float*)d_in[2];
    const float* b1     = (const float*)d_in[3];
    const float* Wroot1 = (const float*)d_in[4];
    const float* Wrel2  = (const float*)d_in[5];
    const float* b2     = (const float*)d_in[6];
    const float* Wroot2 = (const float*)d_in[7];
    const float* Wrel3  = (const float*)d_in[8];
    const float* b3     = (const float*)d_in[9];
    const float* Wroot3 = (const float*)d_in[10];
    const float* fc1W   = (const float*)d_in[11];
    const float* fc1b   = (const float*)d_in[12];
    const float* fc2W   = (const float*)d_in[13];
    const float* fc2b   = (const float*)d_in[14];
    float* out = (float*)d_out;

    const int N = in_sizes[0] / 16;
    const int E = in_sizes[1] / 2;
    const int* e_src = ei;
    const int* e_dst = ei + E;

    const int NB   = (N + BW - 1) / BW;           // 782
    const int NBLK = (E + CHUNK - 1) / CHUNK;     // 391
    const int nbT  = (N + 511) / 512;             // 196

    char* ws = (char*)d_ws;
    size_t off = 0;
    auto alloc = [&](size_t bytes) { char* p = ws + off; off += (bytes + 15) & ~size_t(15); return p; };
    unsigned* stage = (unsigned*)alloc((size_t)NB * REGION * 4);
    int* csr        = (int*)alloc((size_t)NB * REGION * 4);
    int* gcur       = (int*)alloc((size_t)NB * 4);
    int* deg        = (int*)alloc((size_t)N * 4);
    int* rowstart   = (int*)alloc((size_t)N * 4);
    int* ptot_arr   = (int*)alloc((size_t)NB * 4);
    _Float16* t1    = (_Float16*)alloc((size_t)N * 8 * 2);
    _Float16* z1    = (_Float16*)alloc((size_t)N * 8 * 2);
    _Float16* h1    = (_Float16*)alloc((size_t)N * 8 * 2);
    _Float16* t3    = (_Float16*)alloc((size_t)N * 8 * 2);
    _Float16* z3    = (_Float16*)alloc((size_t)N * 8 * 2);

    // bucket cursors start at 0 (reserve offsets are region-relative)
    hipMemsetAsync(gcur, 0, (size_t)NB * 4, stream);

    // 1) transform1 + hist/reserve/scatter (fused, independent halves)
    setup_scatter_kernel<<<nbT + NBLK, 512, 0, stream>>>(
        x, Wrel1, b1, Wroot1, t1, z1, e_src, e_dst, gcur, stage, N, E, NB, nbT);
    // 2) per-bucket LDS counting sort -> csr (coalesced) + layer-1 agg
    csr_agg1_kernel<<<NB, 256, 0, stream>>>(stage, gcur, csr, deg, rowstart,
                                            ptot_arr, t1, z1, h1, N);
    // 3) layer 2 + layer-3 transform (edge-parallel)
    gcn2_edge_kernel<<<NB, 512, 0, stream>>>(h1, rowstart, deg, csr, ptot_arr,
                                             Wrel2, b2, Wroot2, Wrel3, b3, Wroot3,
                                             t3, z3, N);
    // 4) layer 3 + MLP head (edge-parallel)
    agg3_edge_kernel<<<NB, 512, 0, stream>>>(t3, z3, rowstart, deg, csr, ptot_arr,
                                             fc1W, fc1b, fc2W, fc2b, out, N);
}

// Round 22
// 232.308 us; speedup vs baseline: 1.2168x; 1.2168x over previous
//
#include <hip/hip_runtime.h>
#include <math.h>

// ---------------------------------------------------------------------------
// R16: R9 verbatim (225.6 us measured best) + ONE change: csr_agg1 drops the
//      s_p staging buffer (histogram + sort passes read stage directly from
//      global, 2nd read L2-hot). LDS 46->25.6 KB -> 3->6 blocks/CU for the
//      latency-bound fused layer-1 gather.
//     Measured lessons (refuted structures - do not revisit):
//       R5 edge-parallel global/LDS atomic accumulation: 183 us/layer.
//       R6 node-exact global scatter: 260 us (15x write ampl).
//       R8 few-block big-LDS kernels: grid starvation.
//       R11 mega-kernel fusion pinning LDS: 217 us alone (occ 35%).
//       R12 CHUNK 32768 (98 scatter blocks): scatter 56-68 us; 8-way split
//           regressed. R12+R13: scatter invariant to write-bytes AND blocks
//           >=196 -> ~47 us floor (per-edge dependent work). Parked.
//       R14/R15 edge-parallel two-phase agg: 71.5 us/layer at occ 15%
//           (VGPR 100 from 12-wide prefetch) - occupancy beats prefetch.
// ---------------------------------------------------------------------------

#define CHUNK     16384   // edges per scatter block (196 blocks; R9 config)
#define BW        128     // nodes per bucket (dst >> 7)
#define MAXNB     800     // >= NB = 782
#define MAXB_RAW  5376    // raw edges clamp per bucket (mean 4092, +20 sigma)
#define MAXB_PAD  5760    // padded rows clamp (raw + 128*3)
#define REGION    5760    // fixed region stride (ints); 16B-aligned

typedef _Float16 half8 __attribute__((ext_vector_type(8)));

static __device__ __forceinline__ float sigmoidf_(float x) {
    return 1.0f / (1.0f + expf(-x));
}

// exclusive 256-scan; s[255] holds inclusive total afterwards
static __device__ __forceinline__ int scan256_excl(int v, int* s) {
    int tid = threadIdx.x;
    s[tid] = v;
    for (int off = 1; off < 256; off <<= 1) {
        __syncthreads();
        int t = (tid >= off) ? s[tid - off] : 0;
        __syncthreads();
        s[tid] += t;
    }
    __syncthreads();
    return s[tid] - v;
}

// sum of t[idx] over global csr[rs+from..rs+to); from 4-aligned
static __device__ __forceinline__ void gather_sum8(
    const half8* __restrict__ t, const int* __restrict__ csr,
    int rs, int from, int to, float* s) {
#pragma unroll
    for (int c = 0; c < 8; ++c) s[c] = 0.0f;
    int e = from;
    for (; e + 4 <= to; e += 4) {
        int4 ci = *(const int4*)(csr + rs + e);
        half8 v0 = t[ci.x]; half8 v1 = t[ci.y];
        half8 v2 = t[ci.z]; half8 v3 = t[ci.w];
#pragma unroll
        for (int c = 0; c < 8; ++c)
            s[c] += ((float)v0[c] + (float)v1[c]) + ((float)v2[c] + (float)v3[c]);
    }
    for (; e < to; ++e) {
        half8 v = t[csr[rs + e]];
#pragma unroll
        for (int c = 0; c < 8; ++c) s[c] += (float)v[c];
    }
}

// 4-way split gather-mean (agg layers 2/3); full mean lands on all 4 lanes
static __device__ __forceinline__ void quad_gather_mean8(
    const half8* __restrict__ t, const int* __restrict__ csr,
    int rs, int d, int q, float* s) {
    int qs = ((d + 15) >> 4) << 2;            // 4-aligned segment >= d/4
    int from = q * qs; if (from > d) from = d;
    int to = from + qs; if (to > d) to = d;
    gather_sum8(t, csr, rs, from, to, s);
#pragma unroll
    for (int c = 0; c < 8; ++c) s[c] += __shfl_xor(s[c], 1);
#pragma unroll
    for (int c = 0; c < 8; ++c) s[c] += __shfl_xor(s[c], 2);
    float inv = 1.0f / (float)(d > 0 ? d : 1);
#pragma unroll
    for (int c = 0; c < 8; ++c) s[c] *= inv;
}

// ---- fused: transform1 (blocks [0,nbT)) + hist/reserve/scatter -----------
__global__ __launch_bounds__(512)
void setup_scatter_kernel(const float* __restrict__ x, const float* __restrict__ Wrel,
                          const float* __restrict__ bias, const float* __restrict__ Wroot,
                          _Float16* __restrict__ t1, _Float16* __restrict__ z1,
                          const int* __restrict__ src, const int* __restrict__ dst,
                          int* __restrict__ gcur, unsigned* __restrict__ stage,
                          int N, int E, int NB, int nbT) {
    __shared__ float sWr[128], sWo[128], sb[8];
    __shared__ int s_hist[MAXNB];
    __shared__ int s_cur[MAXNB];
    int tid = threadIdx.x, blk = blockIdx.x;

    if (blk < nbT) {
        // ---- transform: t1 = x@Wr1, z1 = x@Wo1 + b1 ----
        if (tid < 128) { sWr[tid] = Wrel[tid]; sWo[tid] = Wroot[tid]; }
        if (tid >= 128 && tid < 136) sb[tid - 128] = bias[tid - 128];
        __syncthreads();
        int node = blk * 512 + tid;
        if (node >= N) return;
        const float4* x4 = (const float4*)x;
        float xv[16];
#pragma unroll
        for (int k = 0; k < 4; ++k) {
            float4 v = x4[node * 4 + k];
            xv[4 * k] = v.x; xv[4 * k + 1] = v.y; xv[4 * k + 2] = v.z; xv[4 * k + 3] = v.w;
        }
        float ta[8], za[8];
#pragma unroll
        for (int j = 0; j < 8; ++j) { ta[j] = 0.0f; za[j] = sb[j]; }
#pragma unroll
        for (int f = 0; f < 16; ++f) {
            float xf = xv[f];
#pragma unroll
            for (int j = 0; j < 8; ++j) {
                ta[j] += xf * sWr[f * 8 + j];
                za[j] += xf * sWo[f * 8 + j];
            }
        }
        half8 th, zh;
#pragma unroll
        for (int j = 0; j < 8; ++j) { th[j] = (_Float16)ta[j]; zh[j] = (_Float16)za[j]; }
        ((half8*)t1)[node] = th;
        ((half8*)z1)[node] = zh;
    } else {
        // ---- per-chunk hist -> global reserve -> LDS-cursor scatter ----
        int chunk = blk - nbT;
        int base = chunk * CHUNK;
        int cnt = E - base; if (cnt > CHUNK) cnt = CHUNK;
        for (int i = tid; i < NB; i += 512) s_hist[i] = 0;
        __syncthreads();
        if (cnt == CHUNK) {
            const int4* d4 = (const int4*)(dst + base);
#pragma unroll
            for (int k = 0; k < CHUNK / 2048; ++k) {
                int4 d = d4[k * 512 + tid];
                atomicAdd(&s_hist[d.x >> 7], 1);
                atomicAdd(&s_hist[d.y >> 7], 1);
                atomicAdd(&s_hist[d.z >> 7], 1);
                atomicAdd(&s_hist[d.w >> 7], 1);
            }
        } else {
            for (int i = tid; i < cnt; i += 512) atomicAdd(&s_hist[dst[base + i] >> 7], 1);
        }
        __syncthreads();
        for (int i = tid; i < NB; i += 512) {
            int hh = s_hist[i];
            s_cur[i] = i * REGION + atomicAdd(&gcur[i], hh);
        }
        __syncthreads();
        if (cnt == CHUNK) {
            const int4* d4 = (const int4*)(dst + base);
            const int4* s4 = (const int4*)(src + base);
#pragma unroll
            for (int k = 0; k < CHUNK / 2048; ++k) {
                int4 d = d4[k * 512 + tid];
                int4 s = s4[k * 512 + tid];
                int dd[4] = {d.x, d.y, d.z, d.w};
                int ss[4] = {s.x, s.y, s.z, s.w};
#pragma unroll
                for (int j = 0; j < 4; ++j) {
                    int pos = atomicAdd(&s_cur[dd[j] >> 7], 1);
                    stage[pos] = ((unsigned)(dd[j] & 127) << 17) | (unsigned)ss[j];
                }
            }
        } else {
            for (int i = tid; i < cnt; i += 512) {
                int d = dst[base + i], s = src[base + i];
                int pos = atomicAdd(&s_cur[d >> 7], 1);
                stage[pos] = ((unsigned)(d & 127) << 17) | (unsigned)s;
            }
        }
    }
}

// ---- per-bucket counting sort + coalesced csr + layer-1 agg --------------
// R16: no s_p staging; histogram and sort passes both read stage from
// global (uint4 coalesced; 2nd read L2-hot). LDS ~25.6 KB -> 6 blocks/CU.
__global__ __launch_bounds__(256)
void csr_agg1_kernel(const unsigned* __restrict__ stage, const int* __restrict__ gcur,
                     int* __restrict__ csr, int* __restrict__ deg,
                     int* __restrict__ rowstart,
                     const _Float16* __restrict__ t1, const _Float16* __restrict__ z1,
                     _Float16* __restrict__ h1, int N) {
    __shared__ int __attribute__((aligned(16))) s_out[MAXB_PAD];
    __shared__ int h[BW], hs[BW], curb[BW];
    __shared__ int s_scan[256];
    int b = blockIdx.x, tid = threadIdx.x;
    int beg = b * REGION;
    int tot = gcur[b]; if (tot > MAXB_RAW) tot = MAXB_RAW;

    const uint4* st4 = (const uint4*)(stage + beg);
    int n4 = tot >> 2;

    // pass 1: per-node histogram from global (coalesced)
    if (tid < BW) h[tid] = 0;
    __syncthreads();
    for (int i = tid; i < n4; i += 256) {
        uint4 p = st4[i];
        atomicAdd(&h[p.x >> 17], 1); atomicAdd(&h[p.y >> 17], 1);
        atomicAdd(&h[p.z >> 17], 1); atomicAdd(&h[p.w >> 17], 1);
    }
    for (int i = (n4 << 2) + tid; i < tot; i += 256) atomicAdd(&h[stage[beg + i] >> 17], 1);
    __syncthreads();

    // exclusive scan of align4(deg) (tid >= BW contribute 0)
    int v = (tid < BW) ? ((h[tid] + 3) & ~3) : 0;
    int excl = scan256_excl(v, s_scan);
    int ptot = s_scan[255]; if (ptot > MAXB_PAD) ptot = MAXB_PAD;
    int dg = 0, myStart = 0;
    if (tid < BW) {
        dg = h[tid]; myStart = excl;
        hs[tid] = myStart; curb[tid] = myStart;
        int node = b * BW + tid;
        if (node < N) { deg[node] = dg; rowstart[node] = beg + myStart; }
    }
    __syncthreads();

    // pass 2: counting-sort scatter into LDS s_out (stage re-read, L2-hot)
    for (int i = tid; i < n4; i += 256) {
        uint4 p = st4[i];
        int pos;
        pos = atomicAdd(&curb[p.x >> 17], 1); s_out[pos] = (int)(p.x & 0x1FFFF);
        pos = atomicAdd(&curb[p.y >> 17], 1); s_out[pos] = (int)(p.y & 0x1FFFF);
        pos = atomicAdd(&curb[p.z >> 17], 1); s_out[pos] = (int)(p.z & 0x1FFFF);
        pos = atomicAdd(&curb[p.w >> 17], 1); s_out[pos] = (int)(p.w & 0x1FFFF);
    }
    for (int i = (n4 << 2) + tid; i < tot; i += 256) {
        unsigned p = stage[beg + i];
        int pos = atomicAdd(&curb[p >> 17], 1);
        s_out[pos] = (int)(p & 0x1FFFF);
    }
    __syncthreads();

    // coalesced csr write (ptot is a multiple of 4)
    int p4 = ptot >> 2;
    int4* csr4 = (int4*)(csr + beg);
    for (int i = tid; i < p4; i += 256) csr4[i] = ((const int4*)s_out)[i];

    // layer-1 aggregation: 2 threads/node, indices from LDS, t1 from L2
    int nd = tid >> 1, half = tid & 1;
    int node = b * BW + nd;
    if (node < N) {
        int rs = hs[nd], d = h[nd];
        int d1 = ((d >> 1) + 3) & ~3; if (d1 > d) d1 = d;
        int from = half ? d1 : 0;
        int to   = half ? d  : d1;
        const half8* t = (const half8*)t1;
        float s[8];
#pragma unroll
        for (int c = 0; c < 8; ++c) s[c] = 0.0f;
        int e = from;
        for (; e + 4 <= to; e += 4) {
            int4 ci = *(const int4*)(s_out + rs + e);
            half8 v0 = t[ci.x]; half8 v1 = t[ci.y];
            half8 v2 = t[ci.z]; half8 v3 = t[ci.w];
#pragma unroll
            for (int c = 0; c < 8; ++c)
                s[c] += ((float)v0[c] + (float)v1[c]) + ((float)v2[c] + (float)v3[c]);
        }
        for (; e < to; ++e) {
            half8 vv = t[s_out[rs + e]];
#pragma unroll
            for (int c = 0; c < 8; ++c) s[c] += (float)vv[c];
        }
#pragma unroll
        for (int c = 0; c < 8; ++c) s[c] += __shfl_xor(s[c], 1);
        if (half == 0) {
            float inv = 1.0f / (float)(d > 0 ? d : 1);
            half8 z = ((const half8*)z1)[node];
            half8 o;
#pragma unroll
            for (int c = 0; c < 8; ++c) o[c] = (_Float16)sigmoidf_(s[c] * inv + (float)z[c]);
            ((half8*)h1)[node] = o;
        }
    }
}

// ---- layer 2 + layer-3 transform; 4 threads per node ---------------------
__global__ __launch_bounds__(256)
void gcn2_fused_kernel(const _Float16* __restrict__ h1,
                       const int* __restrict__ rowstart, const int* __restrict__ deg,
                       const int* __restrict__ csr,
                       const float* __restrict__ W2r, const float* __restrict__ b2,
                       const float* __restrict__ W2o,
                       const float* __restrict__ W3r, const float* __restrict__ b3,
                       const float* __restrict__ W3o,
                       _Float16* __restrict__ t3, _Float16* __restrict__ z3, int n) {
    __shared__ float sW2r[128], sW2o[128], sW3r[128], sW3o[128], sb2[16], sb3[8];
    int tid = threadIdx.x;
    if (tid < 128) {
        sW2r[tid] = W2r[tid]; sW2o[tid] = W2o[tid];
        sW3r[tid] = W3r[tid]; sW3o[tid] = W3o[tid];
    }
    if (tid < 16) sb2[tid] = b2[tid];
    if (tid < 8) sb3[tid] = b3[tid];
    __syncthreads();
    int idx = blockIdx.x * 256 + tid;
    int node = idx >> 2, q = idx & 3;
    if (node >= n) return;

    float m[8];
    quad_gather_mean8((const half8*)h1, csr, rowstart[node], deg[node], q, m);
    half8 sf = ((const half8*)h1)[node];
    float x8[8];
#pragma unroll
    for (int c = 0; c < 8; ++c) x8[c] = (float)sf[c];

    float v16[16];
#pragma unroll
    for (int j = 0; j < 16; ++j) {
        float a = sb2[j];
#pragma unroll
        for (int f = 0; f < 8; ++f)
            a += m[f] * sW2r[f * 16 + j] + x8[f] * sW2o[f * 16 + j];
        v16[j] = sigmoidf_(a);
    }
    float ta[8], za[8];
#pragma unroll
    for (int j = 0; j < 8; ++j) { ta[j] = 0.0f; za[j] = sb3[j]; }
#pragma unroll
    for (int f = 0; f < 16; ++f) {
        float hv = v16[f];
#pragma unroll
        for (int j = 0; j < 8; ++j) {
            ta[j] += hv * sW3r[f * 8 + j];
            za[j] += hv * sW3o[f * 8 + j];
        }
    }
    if (q) return;
    half8 th, zh;
#pragma unroll
    for (int j = 0; j < 8; ++j) { th[j] = (_Float16)ta[j]; zh[j] = (_Float16)za[j]; }
    ((half8*)t3)[node] = th;
    ((half8*)z3)[node] = zh;
}

// ---- layer 3 + full MLP head; 4 threads per node -------------------------
__global__ __launch_bounds__(256)
void agg3_mlp_kernel(const _Float16* __restrict__ t3, const _Float16* __restrict__ z3,
                     const int* __restrict__ rowstart, const int* __restrict__ deg,
                     const int* __restrict__ csr,
                     const float* __restrict__ fc1W, const float* __restrict__ fc1b,
                     const float* __restrict__ fc2W, const float* __restrict__ fc2b,
                     float* __restrict__ out, int n) {
    __shared__ float sW1[256], sb1[32], sW2[32];
    __shared__ float sb2_;
    int tid = threadIdx.x;
    if (tid < 256) sW1[tid] = fc1W[tid];
    if (tid < 32) { sb1[tid] = fc1b[tid]; sW2[tid] = fc2W[tid]; }
    if (tid == 0) sb2_ = fc2b[0];
    __syncthreads();
    int idx = blockIdx.x * 256 + tid;
    int node = idx >> 2, q = idx & 3;
    if (node >= n) return;

    float s[8];
    quad_gather_mean8((const half8*)t3, csr, rowstart[node], deg[node], q, s);
    half8 z = ((const half8*)z3)[node];
    float h[8];
#pragma unroll
    for (int c = 0; c < 8; ++c) h[c] = sigmoidf_(s[c] + (float)z[c]);

    float acc = sb2_;
#pragma unroll
    for (int j = 0; j < 32; ++j) {
        float a = sb1[j];
#pragma unroll
        for (int f = 0; f < 8; ++f) a += h[f] * sW1[f * 32 + j];
        acc += sW2[j] * sigmoidf_(a);
    }
    if (q == 0) out[node] = acc;
}

extern "C" void kernel_launch(void* const* d_in, const int* in_sizes, int n_in,
                              void* d_out, int out_size, void* d_ws, size_t ws_size,
                              hipStream_t stream) {
    const float* x      = (const float*)d_in[0];
    const int*   ei     = (const int*)d_in[1];
    const float* Wrel1  = (const float*)d_in[2];
    const float* b1     = (const float*)d_in[3];
    const float* Wroot1 = (const float*)d_in[4];
    const float* Wrel2  = (const float*)d_in[5];
    const float* b2     = (const float*)d_in[6];
    const float* Wroot2 = (const float*)d_in[7];
    const float* Wrel3  = (const float*)d_in[8];
    const float* b3     = (const float*)d_in[9];
    const float* Wroot3 = (const float*)d_in[10];
    const float* fc1W   = (const float*)d_in[11];
    const float* fc1b   = (const float*)d_in[12];
    const float* fc2W   = (const float*)d_in[13];
    const float* fc2b   = (const float*)d_in[14];
    float* out = (float*)d_out;

    const int N = in_sizes[0] / 16;
    const int E = in_sizes[1] / 2;
    const int* e_src = ei;
    const int* e_dst = ei + E;

    const int NB   = (N + BW - 1) / BW;           // 782
    const int NBLK = (E + CHUNK - 1) / CHUNK;     // 196
    const int nbT  = (N + 511) / 512;             // 196
    const int nbQ  = (4 * N + 255) / 256;         // quad-split agg blocks

    char* ws = (char*)d_ws;
    size_t off = 0;
    auto alloc = [&](size_t bytes) { char* p = ws + off; off += (bytes + 15) & ~size_t(15); return p; };
    unsigned* stage = (unsigned*)alloc((size_t)NB * REGION * 4);
    int* csr        = (int*)alloc((size_t)NB * REGION * 4);
    int* gcur       = (int*)alloc((size_t)NB * 4);
    int* deg        = (int*)alloc((size_t)N * 4);
    int* rowstart   = (int*)alloc((size_t)N * 4);
    _Float16* t1    = (_Float16*)alloc((size_t)N * 8 * 2);
    _Float16* z1    = (_Float16*)alloc((size_t)N * 8 * 2);
    _Float16* h1    = (_Float16*)alloc((size_t)N * 8 * 2);
    _Float16* t3    = (_Float16*)alloc((size_t)N * 8 * 2);
    _Float16* z3    = (_Float16*)alloc((size_t)N * 8 * 2);

    // bucket cursors start at 0 (reserve offsets are region-relative)
    hipMemsetAsync(gcur, 0, (size_t)NB * 4, stream);

    // 1) transform1 + hist/reserve/scatter (fused, independent halves)
    setup_scatter_kernel<<<nbT + NBLK, 512, 0, stream>>>(
        x, Wrel1, b1, Wroot1, t1, z1, e_src, e_dst, gcur, stage, N, E, NB, nbT);
    // 2) per-bucket counting sort (global 2-pass) -> csr + layer-1 agg
    csr_agg1_kernel<<<NB, 256, 0, stream>>>(stage, gcur, csr, deg, rowstart,
                                            t1, z1, h1, N);
    // 3) layer 2 + layer-3 transform
    gcn2_fused_kernel<<<nbQ, 256, 0, stream>>>(h1, rowstart, deg, csr,
                                               Wrel2, b2, Wroot2, Wrel3, b3, Wroot3, t3, z3, N);
    // 4) layer 3 + MLP head
    agg3_mlp_kernel<<<nbQ, 256, 0, stream>>>(t3, z3, rowstart, deg, csr,
                                             fc1W, fc1b, fc2W, fc2b, out, N);
}

// Round 23
// 221.297 us; speedup vs baseline: 1.2774x; 1.0498x over previous
//
#include <hip/hip_runtime.h>
#include <math.h>

// ---------------------------------------------------------------------------
// R17 = R9 verbatim: the session's measured best (225.6 us, round 7).
//     Plateau record: R9 225.6 | R13 226.7 | R4 232.0 | R16 232.3 — four
//     configs within ±3%. All larger structural bets measured worse:
//       R5 edge-parallel atomic accumulation: 183 us/layer.
//       R6 node-exact global scatter: 260 us (WRITE 194 MB, 15x ampl).
//       R8 few-block big-LDS kernels: grid starvation (48.9 us).
//       R11 mega-kernel fusion pinning LDS: 217 us alone (occ 35%).
//       R12 CHUNK 32768 / 8-way split: scatter 56-68 us, agg regressed.
//       R14/R15 edge-parallel two-phase agg: 71.5 us/layer (occ 15%).
//     Every stage is latency-bound (HBM <=20%, VALU <=8%); scatter floor
//     ~47 us invariant to write-bytes (24<->51 MB) and blocks >=196.
//     Structure: setup (transform1 + hist/reserve/scatter, fused) ->
//     csr_agg1 (LDS counting sort + coalesced csr + 2-way layer-1) ->
//     gcn2 (4-way, +layer-3 transform) -> agg3 (4-way, +MLP head).
// ---------------------------------------------------------------------------

#define CHUNK     16384   // edges per scatter block
#define BW        128     // nodes per bucket (dst >> 7)
#define MAXNB     800     // >= NB = 782
#define MAXB_RAW  5376    // raw edges clamp per bucket (mean 4092, +20 sigma)
#define MAXB_PAD  5760    // padded rows clamp (raw + 128*3)
#define REGION    5760    // fixed region stride (ints); 16B-aligned

typedef _Float16 half8 __attribute__((ext_vector_type(8)));

static __device__ __forceinline__ float sigmoidf_(float x) {
    return 1.0f / (1.0f + expf(-x));
}

// exclusive 256-scan; s[255] holds inclusive total afterwards
static __device__ __forceinline__ int scan256_excl(int v, int* s) {
    int tid = threadIdx.x;
    s[tid] = v;
    for (int off = 1; off < 256; off <<= 1) {
        __syncthreads();
        int t = (tid >= off) ? s[tid - off] : 0;
        __syncthreads();
        s[tid] += t;
    }
    __syncthreads();
    return s[tid] - v;
}

// sum of t[idx] over global csr[rs+from..rs+to); from 4-aligned
static __device__ __forceinline__ void gather_sum8(
    const half8* __restrict__ t, const int* __restrict__ csr,
    int rs, int from, int to, float* s) {
#pragma unroll
    for (int c = 0; c < 8; ++c) s[c] = 0.0f;
    int e = from;
    for (; e + 4 <= to; e += 4) {
        int4 ci = *(const int4*)(csr + rs + e);
        half8 v0 = t[ci.x]; half8 v1 = t[ci.y];
        half8 v2 = t[ci.z]; half8 v3 = t[ci.w];
#pragma unroll
        for (int c = 0; c < 8; ++c)
            s[c] += ((float)v0[c] + (float)v1[c]) + ((float)v2[c] + (float)v3[c]);
    }
    for (; e < to; ++e) {
        half8 v = t[csr[rs + e]];
#pragma unroll
        for (int c = 0; c < 8; ++c) s[c] += (float)v[c];
    }
}

// 4-way split gather-mean (agg layers 2/3); full mean lands on all 4 lanes
static __device__ __forceinline__ void quad_gather_mean8(
    const half8* __restrict__ t, const int* __restrict__ csr,
    int rs, int d, int q, float* s) {
    int qs = ((d + 15) >> 4) << 2;            // 4-aligned segment >= d/4
    int from = q * qs; if (from > d) from = d;
    int to = from + qs; if (to > d) to = d;
    gather_sum8(t, csr, rs, from, to, s);
#pragma unroll
    for (int c = 0; c < 8; ++c) s[c] += __shfl_xor(s[c], 1);
#pragma unroll
    for (int c = 0; c < 8; ++c) s[c] += __shfl_xor(s[c], 2);
    float inv = 1.0f / (float)(d > 0 ? d : 1);
#pragma unroll
    for (int c = 0; c < 8; ++c) s[c] *= inv;
}

// ---- fused: transform1 (blocks [0,nbT)) + hist/reserve/scatter -----------
__global__ __launch_bounds__(512)
void setup_scatter_kernel(const float* __restrict__ x, const float* __restrict__ Wrel,
                          const float* __restrict__ bias, const float* __restrict__ Wroot,
                          _Float16* __restrict__ t1, _Float16* __restrict__ z1,
                          const int* __restrict__ src, const int* __restrict__ dst,
                          int* __restrict__ gcur, unsigned* __restrict__ stage,
                          int N, int E, int NB, int nbT) {
    __shared__ float sWr[128], sWo[128], sb[8];
    __shared__ int s_hist[MAXNB];
    __shared__ int s_cur[MAXNB];
    int tid = threadIdx.x, blk = blockIdx.x;

    if (blk < nbT) {
        // ---- transform: t1 = x@Wr1, z1 = x@Wo1 + b1 ----
        if (tid < 128) { sWr[tid] = Wrel[tid]; sWo[tid] = Wroot[tid]; }
        if (tid >= 128 && tid < 136) sb[tid - 128] = bias[tid - 128];
        __syncthreads();
        int node = blk * 512 + tid;
        if (node >= N) return;
        const float4* x4 = (const float4*)x;
        float xv[16];
#pragma unroll
        for (int k = 0; k < 4; ++k) {
            float4 v = x4[node * 4 + k];
            xv[4 * k] = v.x; xv[4 * k + 1] = v.y; xv[4 * k + 2] = v.z; xv[4 * k + 3] = v.w;
        }
        float ta[8], za[8];
#pragma unroll
        for (int j = 0; j < 8; ++j) { ta[j] = 0.0f; za[j] = sb[j]; }
#pragma unroll
        for (int f = 0; f < 16; ++f) {
            float xf = xv[f];
#pragma unroll
            for (int j = 0; j < 8; ++j) {
                ta[j] += xf * sWr[f * 8 + j];
                za[j] += xf * sWo[f * 8 + j];
            }
        }
        half8 th, zh;
#pragma unroll
        for (int j = 0; j < 8; ++j) { th[j] = (_Float16)ta[j]; zh[j] = (_Float16)za[j]; }
        ((half8*)t1)[node] = th;
        ((half8*)z1)[node] = zh;
    } else {
        // ---- per-chunk hist -> global reserve -> LDS-cursor scatter ----
        int chunk = blk - nbT;
        int base = chunk * CHUNK;
        int cnt = E - base; if (cnt > CHUNK) cnt = CHUNK;
        for (int i = tid; i < NB; i += 512) s_hist[i] = 0;
        __syncthreads();
        if (cnt == CHUNK) {
            const int4* d4 = (const int4*)(dst + base);
#pragma unroll
            for (int k = 0; k < CHUNK / 2048; ++k) {
                int4 d = d4[k * 512 + tid];
                atomicAdd(&s_hist[d.x >> 7], 1);
                atomicAdd(&s_hist[d.y >> 7], 1);
                atomicAdd(&s_hist[d.z >> 7], 1);
                atomicAdd(&s_hist[d.w >> 7], 1);
            }
        } else {
            for (int i = tid; i < cnt; i += 512) atomicAdd(&s_hist[dst[base + i] >> 7], 1);
        }
        __syncthreads();
        for (int i = tid; i < NB; i += 512) {
            int hh = s_hist[i];
            s_cur[i] = i * REGION + atomicAdd(&gcur[i], hh);
        }
        __syncthreads();
        if (cnt == CHUNK) {
            const int4* d4 = (const int4*)(dst + base);
            const int4* s4 = (const int4*)(src + base);
#pragma unroll
            for (int k = 0; k < CHUNK / 2048; ++k) {
                int4 d = d4[k * 512 + tid];
                int4 s = s4[k * 512 + tid];
                int dd[4] = {d.x, d.y, d.z, d.w};
                int ss[4] = {s.x, s.y, s.z, s.w};
#pragma unroll
                for (int j = 0; j < 4; ++j) {
                    int pos = atomicAdd(&s_cur[dd[j] >> 7], 1);
                    stage[pos] = ((unsigned)(dd[j] & 127) << 17) | (unsigned)ss[j];
                }
            }
        } else {
            for (int i = tid; i < cnt; i += 512) {
                int d = dst[base + i], s = src[base + i];
                int pos = atomicAdd(&s_cur[d >> 7], 1);
                stage[pos] = ((unsigned)(d & 127) << 17) | (unsigned)s;
            }
        }
    }
}

// ---- per-bucket counting sort (LDS-resident) + coalesced csr + agg1 ------
__global__ __launch_bounds__(256)
void csr_agg1_kernel(const unsigned* __restrict__ stage, const int* __restrict__ gcur,
                     int* __restrict__ csr, int* __restrict__ deg,
                     int* __restrict__ rowstart,
                     const _Float16* __restrict__ t1, const _Float16* __restrict__ z1,
                     _Float16* __restrict__ h1, int N) {
    __shared__ unsigned __attribute__((aligned(16))) s_p[MAXB_RAW];
    __shared__ int __attribute__((aligned(16))) s_out[MAXB_PAD];
    __shared__ int h[BW], hs[BW], curb[BW];
    __shared__ int s_scan[256];
    int b = blockIdx.x, tid = threadIdx.x;
    int beg = b * REGION;
    int tot = gcur[b]; if (tot > MAXB_RAW) tot = MAXB_RAW;

    // coalesced region read into LDS
    const uint4* st4 = (const uint4*)(stage + beg);
    int n4 = tot >> 2;
    for (int i = tid; i < n4; i += 256) ((uint4*)s_p)[i] = st4[i];
    for (int i = (n4 << 2) + tid; i < tot; i += 256) s_p[i] = stage[beg + i];
    if (tid < BW) h[tid] = 0;
    __syncthreads();

    // per-node histogram
    for (int i = tid; i < tot; i += 256) atomicAdd(&h[s_p[i] >> 17], 1);
    __syncthreads();

    // exclusive scan of align4(deg) (tid >= BW contribute 0)
    int v = (tid < BW) ? ((h[tid] + 3) & ~3) : 0;
    int excl = scan256_excl(v, s_scan);
    int ptot = s_scan[255];
    int dg = 0, myStart = 0;
    if (tid < BW) {
        dg = h[tid]; myStart = excl;
        hs[tid] = myStart; curb[tid] = myStart;
        int node = b * BW + tid;
        if (node < N) { deg[node] = dg; rowstart[node] = beg + myStart; }
    }
    __syncthreads();

    // counting-sort scatter into LDS s_out
    for (int i = tid; i < tot; i += 256) {
        unsigned p = s_p[i];
        int pos = atomicAdd(&curb[p >> 17], 1);
        s_out[pos] = (int)(p & 0x1FFFF);
    }
    __syncthreads();

    // coalesced csr write (ptot is a multiple of 4)
    if (ptot > MAXB_PAD) ptot = MAXB_PAD;
    int p4 = ptot >> 2;
    int4* csr4 = (int4*)(csr + beg);
    for (int i = tid; i < p4; i += 256) csr4[i] = ((const int4*)s_out)[i];

    // layer-1 aggregation: 2 threads/node, indices from LDS, t1 from L2
    int nd = tid >> 1, half = tid & 1;
    int node = b * BW + nd;
    if (node < N) {
        int rs = hs[nd], d = h[nd];
        int d1 = ((d >> 1) + 3) & ~3; if (d1 > d) d1 = d;
        int from = half ? d1 : 0;
        int to   = half ? d  : d1;
        const half8* t = (const half8*)t1;
        float s[8];
#pragma unroll
        for (int c = 0; c < 8; ++c) s[c] = 0.0f;
        int e = from;
        for (; e + 4 <= to; e += 4) {
            int4 ci = *(const int4*)(s_out + rs + e);
            half8 v0 = t[ci.x]; half8 v1 = t[ci.y];
            half8 v2 = t[ci.z]; half8 v3 = t[ci.w];
#pragma unroll
            for (int c = 0; c < 8; ++c)
                s[c] += ((float)v0[c] + (float)v1[c]) + ((float)v2[c] + (float)v3[c]);
        }
        for (; e < to; ++e) {
            half8 vv = t[s_out[rs + e]];
#pragma unroll
            for (int c = 0; c < 8; ++c) s[c] += (float)vv[c];
        }
#pragma unroll
        for (int c = 0; c < 8; ++c) s[c] += __shfl_xor(s[c], 1);
        if (half == 0) {
            float inv = 1.0f / (float)(d > 0 ? d : 1);
            half8 z = ((const half8*)z1)[node];
            half8 o;
#pragma unroll
            for (int c = 0; c < 8; ++c) o[c] = (_Float16)sigmoidf_(s[c] * inv + (float)z[c]);
            ((half8*)h1)[node] = o;
        }
    }
}

// ---- layer 2 + layer-3 transform; 4 threads per node ---------------------
__global__ __launch_bounds__(256)
void gcn2_fused_kernel(const _Float16* __restrict__ h1,
                       const int* __restrict__ rowstart, const int* __restrict__ deg,
                       const int* __restrict__ csr,
                       const float* __restrict__ W2r, const float* __restrict__ b2,
                       const float* __restrict__ W2o,
                       const float* __restrict__ W3r, const float* __restrict__ b3,
                       const float* __restrict__ W3o,
                       _Float16* __restrict__ t3, _Float16* __restrict__ z3, int n) {
    __shared__ float sW2r[128], sW2o[128], sW3r[128], sW3o[128], sb2[16], sb3[8];
    int tid = threadIdx.x;
    if (tid < 128) {
        sW2r[tid] = W2r[tid]; sW2o[tid] = W2o[tid];
        sW3r[tid] = W3r[tid]; sW3o[tid] = W3o[tid];
    }
    if (tid < 16) sb2[tid] = b2[tid];
    if (tid < 8) sb3[tid] = b3[tid];
    __syncthreads();
    int idx = blockIdx.x * 256 + tid;
    int node = idx >> 2, q = idx & 3;
    if (node >= n) return;

    float m[8];
    quad_gather_mean8((const half8*)h1, csr, rowstart[node], deg[node], q, m);
    half8 sf = ((const half8*)h1)[node];
    float x8[8];
#pragma unroll
    for (int c = 0; c < 8; ++c) x8[c] = (float)sf[c];

    float v16[16];
#pragma unroll
    for (int j = 0; j < 16; ++j) {
        float a = sb2[j];
#pragma unroll
        for (int f = 0; f < 8; ++f)
            a += m[f] * sW2r[f * 16 + j] + x8[f] * sW2o[f * 16 + j];
        v16[j] = sigmoidf_(a);
    }
    float ta[8], za[8];
#pragma unroll
    for (int j = 0; j < 8; ++j) { ta[j] = 0.0f; za[j] = sb3[j]; }
#pragma unroll
    for (int f = 0; f < 16; ++f) {
        float hv = v16[f];
#pragma unroll
        for (int j = 0; j < 8; ++j) {
            ta[j] += hv * sW3r[f * 8 + j];
            za[j] += hv * sW3o[f * 8 + j];
        }
    }
    if (q) return;
    half8 th, zh;
#pragma unroll
    for (int j = 0; j < 8; ++j) { th[j] = (_Float16)ta[j]; zh[j] = (_Float16)za[j]; }
    ((half8*)t3)[node] = th;
    ((half8*)z3)[node] = zh;
}

// ---- layer 3 + full MLP head; 4 threads per node -------------------------
__global__ __launch_bounds__(256)
void agg3_mlp_kernel(const _Float16* __restrict__ t3, const _Float16* __restrict__ z3,
                     const int* __restrict__ rowstart, const int* __restrict__ deg,
                     const int* __restrict__ csr,
                     const float* __restrict__ fc1W, const float* __restrict__ fc1b,
                     const float* __restrict__ fc2W, const float* __restrict__ fc2b,
                     float* __restrict__ out, int n) {
    __shared__ float sW1[256], sb1[32], sW2[32];
    __shared__ float sb2_;
    int tid = threadIdx.x;
    if (tid < 256) sW1[tid] = fc1W[tid];
    if (tid < 32) { sb1[tid] = fc1b[tid]; sW2[tid] = fc2W[tid]; }
    if (tid == 0) sb2_ = fc2b[0];
    __syncthreads();
    int idx = blockIdx.x * 256 + tid;
    int node = idx >> 2, q = idx & 3;
    if (node >= n) return;

    float s[8];
    quad_gather_mean8((const half8*)t3, csr, rowstart[node], deg[node], q, s);
    half8 z = ((const half8*)z3)[node];
    float h[8];
#pragma unroll
    for (int c = 0; c < 8; ++c) h[c] = sigmoidf_(s[c] + (float)z[c]);

    float acc = sb2_;
#pragma unroll
    for (int j = 0; j < 32; ++j) {
        float a = sb1[j];
#pragma unroll
        for (int f = 0; f < 8; ++f) a += h[f] * sW1[f * 32 + j];
        acc += sW2[j] * sigmoidf_(a);
    }
    if (q == 0) out[node] = acc;
}

extern "C" void kernel_launch(void* const* d_in, const int* in_sizes, int n_in,
                              void* d_out, int out_size, void* d_ws, size_t ws_size,
                              hipStream_t stream) {
    const float* x      = (const float*)d_in[0];
    const int*   ei     = (const int*)d_in[1];
    const float* Wrel1  = (const float*)d_in[2];
    const float* b1     = (const float*)d_in[3];
    const float* Wroot1 = (const float*)d_in[4];
    const float* Wrel2  = (const float*)d_in[5];
    const float* b2     = (const float*)d_in[6];
    const float* Wroot2 = (const float*)d_in[7];
    const float* Wrel3  = (const float*)d_in[8];
    const float* b3     = (const float*)d_in[9];
    const float* Wroot3 = (const float*)d_in[10];
    const float* fc1W   = (const float*)d_in[11];
    const float* fc1b   = (const float*)d_in[12];
    const float* fc2W   = (const float*)d_in[13];
    const float* fc2b   = (const float*)d_in[14];
    float* out = (float*)d_out;

    const int N = in_sizes[0] / 16;
    const int E = in_sizes[1] / 2;
    const int* e_src = ei;
    const int* e_dst = ei + E;

    const int NB   = (N + BW - 1) / BW;           // 782
    const int NBLK = (E + CHUNK - 1) / CHUNK;     // 196
    const int nbT  = (N + 511) / 512;             // 196
    const int nbQ  = (4 * N + 255) / 256;         // quad-split agg blocks

    char* ws = (char*)d_ws;
    size_t off = 0;
    auto alloc = [&](size_t bytes) { char* p = ws + off; off += (bytes + 15) & ~size_t(15); return p; };
    unsigned* stage = (unsigned*)alloc((size_t)NB * REGION * 4);
    int* csr        = (int*)alloc((size_t)NB * REGION * 4);
    int* gcur       = (int*)alloc((size_t)NB * 4);
    int* deg        = (int*)alloc((size_t)N * 4);
    int* rowstart   = (int*)alloc((size_t)N * 4);
    _Float16* t1    = (_Float16*)alloc((size_t)N * 8 * 2);
    _Float16* z1    = (_Float16*)alloc((size_t)N * 8 * 2);
    _Float16* h1    = (_Float16*)alloc((size_t)N * 8 * 2);
    _Float16* t3    = (_Float16*)alloc((size_t)N * 8 * 2);
    _Float16* z3    = (_Float16*)alloc((size_t)N * 8 * 2);

    // bucket cursors start at 0 (reserve offsets are region-relative)
    hipMemsetAsync(gcur, 0, (size_t)NB * 4, stream);

    // 1) transform1 + hist/reserve/scatter (fused, independent halves)
    setup_scatter_kernel<<<nbT + NBLK, 512, 0, stream>>>(
        x, Wrel1, b1, Wroot1, t1, z1, e_src, e_dst, gcur, stage, N, E, NB, nbT);
    // 2) per-bucket LDS counting sort -> csr (coalesced) + layer-1 agg
    csr_agg1_kernel<<<NB, 256, 0, stream>>>(stage, gcur, csr, deg, rowstart,
                                            t1, z1, h1, N);
    // 3) layer 2 + layer-3 transform
    gcn2_fused_kernel<<<nbQ, 256, 0, stream>>>(h1, rowstart, deg, csr,
                                               Wrel2, b2, Wroot2, Wrel3, b3, Wroot3, t3, z3, N);
    // 4) layer 3 + MLP head
    agg3_mlp_kernel<<<nbQ, 256, 0, stream>>>(t3, z3, rowstart, deg, csr,
                                             fc1W, fc1b, fc2W, fc2b, out, N);
}